// Round 9
// baseline (286.860 us; speedup 1.0000x reference)
//
#include <hip/hip_runtime.h>

// DiagLRConv: out[n,o,h,w] = sum_{k,i} fw[o,i,k] * x[n,i,h+k-2,w+k-2]
// x: (16,16,512,512) fp32, fw: (16,16,5) fp32, out fp32.
//
// R9 structure: two passes.
//  Pass 1: repack x (NCHW fp32) -> padded NHWC bf16 in d_ws: [n][517][517][16].
//          2-px zero border = conv zero-padding, written every call.
//  Pass 2: LDS-free MFMA. A-fragment K-slice (8 ch at one (r,c)) is ONE
//          contiguous dwordx4 load from the NHWC buffer. Per 16x16 tile:
//          3 loads + 3 mfma_f32_16x16x32_bf16 + 1 dwordx4 store. No LDS,
//          no barriers, no masks (tap-5 pad column killed by zeroed W frag).
// Fragment mappings carried over from R5-R8 (numerically verified):
//   A lane l: m=px=l&15, K-slot=(l>>4)*8+j -> tap=2s+(l>>5), i=((l>>4)&1)*8+j
//   B (weights) same K mapping, n=o=l&15 ; D: col=o=l&15, row=px=(l>>4)*4+reg.

#define HH    512
#define WW    512
#define CH    16
#define KK    5
#define IMG   (HH * WW)
#define CHIMG (CH * IMG)
#define PH    517                 // padded spatial dim (2 left, 3 right: tap-5 safe)
#define PIMG  (PH * PH)
#define NEED_WS ((size_t)16 * PIMG * CH * 2)   // 136.9 MB bf16

typedef __attribute__((ext_vector_type(8))) short bf16x8;
typedef __attribute__((ext_vector_type(4))) float f32x4;
typedef __attribute__((ext_vector_type(4))) int   i32x4;

union I4S8 { i32x4 i; bf16x8 s; };

__device__ __forceinline__ unsigned cvt_pk_bf16(float lo, float hi) {
    unsigned r;
    asm("v_cvt_pk_bf16_f32 %0, %1, %2" : "=v"(r) : "v"(lo), "v"(hi));
    return r;
}

// ---------------- pass 1: NCHW fp32 -> padded NHWC bf16 ---------------------
__global__ __launch_bounds__(256)
void repack_nhwc_bf16(const float* __restrict__ x,
                      unsigned short* __restrict__ ws)
{
    const int n  = blockIdx.y;
    const int rp = blockIdx.x;              // padded row 0..516
    const int r  = rp - 2;
    const bool rok = (unsigned)r < (unsigned)HH;

    const float* __restrict__ xn = x + (size_t)n * CHIMG;
    unsigned short* __restrict__ wrow =
        ws + ((size_t)n * PIMG + (size_t)rp * PH) * CH;

    for (int wp = threadIdx.x; wp < PH; wp += 256) {
        const int w = wp - 2;
        i32x4 lo = (i32x4){0, 0, 0, 0};
        i32x4 hi = (i32x4){0, 0, 0, 0};
        if (rok & ((unsigned)w < (unsigned)WW)) {
            const float* __restrict__ p = xn + (size_t)r * WW + w;
            float v[16];
#pragma unroll
            for (int c = 0; c < 16; ++c) v[c] = p[(size_t)c * IMG];
            lo.x = (int)cvt_pk_bf16(v[0],  v[1]);
            lo.y = (int)cvt_pk_bf16(v[2],  v[3]);
            lo.z = (int)cvt_pk_bf16(v[4],  v[5]);
            lo.w = (int)cvt_pk_bf16(v[6],  v[7]);
            hi.x = (int)cvt_pk_bf16(v[8],  v[9]);
            hi.y = (int)cvt_pk_bf16(v[10], v[11]);
            hi.z = (int)cvt_pk_bf16(v[12], v[13]);
            hi.w = (int)cvt_pk_bf16(v[14], v[15]);
        }
        // 32B contiguous per lane -> fully coalesced wave stores
        *(i32x4*)(wrow + (size_t)wp * CH)     = lo;   // ch 0..7
        *(i32x4*)(wrow + (size_t)wp * CH + 8) = hi;   // ch 8..15
    }
}

// ---------------- pass 2: LDS-free MFMA conv --------------------------------
__global__ __launch_bounds__(256)
void conv_nhwc_mfma(const unsigned short* __restrict__ ws,
                    const float* __restrict__ fw,
                    float* __restrict__ out)
{
    // 8192 blocks = 8 XCDs x 1024 contiguous (2 images of h each) — bijective.
    const int bid = blockIdx.x;
    const int swz = ((bid & 7) << 10) | (bid >> 3);
    const int n = swz >> 9;          // 0..15
    const int h = swz & 511;         // 0..511

    const int tid  = threadIdx.x;
    const int wv   = tid >> 6;
    const int lane = tid & 63;
    const int px   = lane & 15;
    const int ihl  = (lane >> 4) & 1;
    const int tb   = lane >> 5;

    // W fragments (B operand) — verified R5-R8. tap==5 -> zero.
    bf16x8 wfrag[3];
#pragma unroll
    for (int s = 0; s < 3; ++s) {
        const int tap = 2 * s + tb;
        I4S8 a;
        a.i = (i32x4){0, 0, 0, 0};
        if (tap < KK) {
            const float* __restrict__ wp = fw + ((size_t)px * CH + ihl * 8) * KK + tap;
            a.i.x = (int)cvt_pk_bf16(wp[0 * KK], wp[1 * KK]);
            a.i.y = (int)cvt_pk_bf16(wp[2 * KK], wp[3 * KK]);
            a.i.z = (int)cvt_pk_bf16(wp[4 * KK], wp[5 * KK]);
            a.i.w = (int)cvt_pk_bf16(wp[6 * KK], wp[7 * KK]);
        }
        wfrag[s] = a.s;
    }

    // A-side per-lane element offsets into padded NHWC (no clamps needed:
    // r'=h+tap<=516, c'<=516 both in-bounds; border cells are exact zeros).
    const unsigned short* __restrict__ wsn = ws + (size_t)n * PIMG * CH;
    int loff[3];
#pragma unroll
    for (int s = 0; s < 3; ++s) {
        const int tap = 2 * s + tb;
        loff[s] = ((h + tap) * PH + px + tap) * CH + ihl * 8;
    }

    float* __restrict__ outn = out + (size_t)n * CHIMG + (size_t)h * WW;
    const int o  = lane & 15;
    const int pq = (lane >> 4) << 2;

#pragma unroll
    for (int gi = 0; gi < 8; ++gi) {
        const int g  = wv * 8 + gi;          // w-tile 0..31
        const int cb = g * (16 * CH);        // element offset of tile base
        I4S8 a0, a1, a2;
        a0.i = *(const i32x4*)(wsn + loff[0] + cb);
        a1.i = *(const i32x4*)(wsn + loff[1] + cb);
        a2.i = *(const i32x4*)(wsn + loff[2] + cb);
        f32x4 acc = (f32x4){0.f, 0.f, 0.f, 0.f};
        acc = __builtin_amdgcn_mfma_f32_16x16x32_bf16(a0.s, wfrag[0], acc, 0, 0, 0);
        acc = __builtin_amdgcn_mfma_f32_16x16x32_bf16(a1.s, wfrag[1], acc, 0, 0, 0);
        acc = __builtin_amdgcn_mfma_f32_16x16x32_bf16(a2.s, wfrag[2], acc, 0, 0, 0);
        *(f32x4*)(outn + (size_t)o * IMG + g * 16 + pq) = acc;
    }
}

// ---------------- fallback (R5 kernel, proven 157 us) -----------------------
#define F_RI 20
#define F_WI 68
#define F_NCHUNK 40

__global__ __launch_bounds__(256)
void fallback_r5(const float* __restrict__ x,
                 const float* __restrict__ fw,
                 float* __restrict__ out)
{
    __shared__ i32x4 xl[F_NCHUNK * F_WI];

    const int tid = threadIdx.x;
    const int bid = blockIdx.x;
    const int swz = ((bid & 7) << 9) | (bid >> 3);
    const int n  = swz >> 8;
    const int ht = (swz >> 3) & 31;
    const int wt = swz & 7;
    const int h0 = ht * 16;
    const int w0 = wt * 64;

    const int wv   = tid >> 6;
    const int lane = tid & 63;

    const float* __restrict__ xn = x + (size_t)n * CHIMG;

#pragma unroll
    for (int u = 0; u < 10; ++u) {
        const int unit = u * 4 + wv;
        const int ri = unit >> 1;
        const int ih = unit & 1;
        const int r  = h0 - 2 + ri;
        const int w  = w0 - 2 + lane;
        const bool ok = ((unsigned)r < (unsigned)HH) & ((unsigned)w < (unsigned)WW);
        const int rc = r < 0 ? 0 : (r > HH - 1 ? HH - 1 : r);
        const int wc = w < 0 ? 0 : (w > WW - 1 ? WW - 1 : w);
        const float* __restrict__ p8 = xn + (size_t)(ih * 8) * IMG + (size_t)rc * WW + wc;
        float v0 = p8[0 * (size_t)IMG], v1 = p8[1 * (size_t)IMG];
        float v2 = p8[2 * (size_t)IMG], v3 = p8[3 * (size_t)IMG];
        float v4 = p8[4 * (size_t)IMG], v5 = p8[5 * (size_t)IMG];
        float v6 = p8[6 * (size_t)IMG], v7 = p8[7 * (size_t)IMG];
        if (!ok) { v0=v1=v2=v3=v4=v5=v6=v7 = 0.f; }
        i32x4 pk;
        pk.x = (int)cvt_pk_bf16(v0, v1);
        pk.y = (int)cvt_pk_bf16(v2, v3);
        pk.z = (int)cvt_pk_bf16(v4, v5);
        pk.w = (int)cvt_pk_bf16(v6, v7);
        xl[unit * F_WI + lane] = pk;
    }
    if (tid < 160) {
        const int ri  = tid >> 3;
        const int rem = tid & 7;
        const int wi  = 64 + (rem & 3);
        const int ih  = rem >> 2;
        const int r   = h0 - 2 + ri;
        const int w   = w0 - 2 + wi;
        const bool ok = ((unsigned)r < (unsigned)HH) & ((unsigned)w < (unsigned)WW);
        const int rc = r < 0 ? 0 : (r > HH - 1 ? HH - 1 : r);
        const int wc = w < 0 ? 0 : (w > WW - 1 ? WW - 1 : w);
        const float* __restrict__ p8 = xn + (size_t)(ih * 8) * IMG + (size_t)rc * WW + wc;
        float v0 = p8[0 * (size_t)IMG], v1 = p8[1 * (size_t)IMG];
        float v2 = p8[2 * (size_t)IMG], v3 = p8[3 * (size_t)IMG];
        float v4 = p8[4 * (size_t)IMG], v5 = p8[5 * (size_t)IMG];
        float v6 = p8[6 * (size_t)IMG], v7 = p8[7 * (size_t)IMG];
        if (!ok) { v0=v1=v2=v3=v4=v5=v6=v7 = 0.f; }
        i32x4 pk;
        pk.x = (int)cvt_pk_bf16(v0, v1);
        pk.y = (int)cvt_pk_bf16(v2, v3);
        pk.z = (int)cvt_pk_bf16(v4, v5);
        pk.w = (int)cvt_pk_bf16(v6, v7);
        xl[(ri * 2 + ih) * F_WI + wi] = pk;
    }

    const int px  = lane & 15;
    const int ihl = (lane >> 4) & 1;
    const int tb  = lane >> 5;

    bf16x8 afrag[3];
#pragma unroll
    for (int s = 0; s < 3; ++s) {
        const int tap = 2 * s + tb;
        I4S8 a;
        a.i = (i32x4){0, 0, 0, 0};
        if (tap < KK) {
            const float* __restrict__ wp = fw + ((size_t)px * CH + ihl * 8) * KK + tap;
            a.i.x = (int)cvt_pk_bf16(wp[0 * KK], wp[1 * KK]);
            a.i.y = (int)cvt_pk_bf16(wp[2 * KK], wp[3 * KK]);
            a.i.z = (int)cvt_pk_bf16(wp[4 * KK], wp[5 * KK]);
            a.i.w = (int)cvt_pk_bf16(wp[6 * KK], wp[7 * KK]);
        }
        afrag[s] = a.s;
    }

    __syncthreads();

    f32x4 acc[4][4];
#pragma unroll
    for (int yy = 0; yy < 4; ++yy)
#pragma unroll
        for (int g = 0; g < 4; ++g) acc[yy][g] = (f32x4){0.f, 0.f, 0.f, 0.f};

    const int ybase = wv * 4;
#pragma unroll
    for (int yy = 0; yy < 4; ++yy) {
#pragma unroll
        for (int s = 0; s < 3; ++s) {
            const int tap = 2 * s + tb;
            int ri = ybase + yy + tap;
            ri = ri > F_RI - 1 ? F_RI - 1 : ri;
            const int c = ri * 2 + ihl;
#pragma unroll
            for (int g = 0; g < 4; ++g) {
                int wi = g * 16 + px + tap;
                wi = wi > F_WI - 1 ? F_WI - 1 : wi;
                I4S8 b;
                b.i = xl[c * F_WI + wi];
                acc[yy][g] = __builtin_amdgcn_mfma_f32_16x16x32_bf16(
                    b.s, afrag[s], acc[yy][g], 0, 0, 0);
            }
        }
    }

    float* __restrict__ on = out + (size_t)n * CHIMG;
    const int o  = lane & 15;
    const int pq = (lane >> 4) << 2;
#pragma unroll
    for (int yy = 0; yy < 4; ++yy) {
        const int h = h0 + ybase + yy;
#pragma unroll
        for (int g = 0; g < 4; ++g) {
            float* __restrict__ dst =
                on + (size_t)o * IMG + (size_t)h * WW + (w0 + g * 16 + pq);
            *(f32x4*)dst = acc[yy][g];
        }
    }
}

extern "C" void kernel_launch(void* const* d_in, const int* in_sizes, int n_in,
                              void* d_out, int out_size, void* d_ws, size_t ws_size,
                              hipStream_t stream)
{
    const float* x  = (const float*)d_in[0];
    const float* fw = (const float*)d_in[1];
    float* out      = (float*)d_out;

    if (ws_size >= NEED_WS) {
        unsigned short* ws = (unsigned short*)d_ws;
        repack_nhwc_bf16<<<dim3(PH, 16), dim3(256), 0, stream>>>(x, ws);
        conv_nhwc_mfma<<<dim3(8192), dim3(256), 0, stream>>>(ws, fw, out);
    } else {
        fallback_r5<<<dim3(4096), dim3(256), 0, stream>>>(x, fw, out);
    }
}

// Round 10
// 251.906 us; speedup vs baseline: 1.1388x; 1.1388x over previous
//
#include <hip/hip_runtime.h>

// DiagLRConv: out[n,o,h,w] = sum_{k,i} fw[o,i,k] * x[n,i,h+k-2,w+k-2]
// x: (16,16,512,512) fp32, fw: (16,16,5) fp32, out fp32.
//
// R10: two passes.
//  Pass 1: NCHW fp32 -> zero-padded NHWC bf16 ws [n][517 rows][520 cols][16ch]
//          (row rp = input r+2, col cp = input w+2; borders exact zeros).
//  Pass 2: per block stage a [2half][12r][68c] bf16 tile into LDS with
//          global_load_lds width-16 (no VGPRs -> compiler cannot serialize,
//          the R4/R6/R7/R9 failure mode). Hot loop: 3 ds_read_b128 + 3 MFMA
//          + 1 dwordx4 store per 16x16 tile. No cvt, no masks in hot loop.
// Fragment mappings verified R5-R9:
//   X-frag lane l: m=px=l&15, K-slot=(l>>4)*8+j -> tap=2s+(l>>5), i=((l>>4)&1)*8+j
//   W-frag same K mapping, n=o=l&15 ; D: col=o=l&15, row=px=(l>>4)*4+reg.

#define HH    512
#define WW    512
#define CH    16
#define KK    5
#define IMG   (HH * WW)
#define CHIMG (CH * IMG)

#define PROWS 517
#define PCOLS 520
#define NEED_WS ((size_t)16 * PROWS * PCOLS * CH * 2)   // 137.6 MB

// pass-2 tile geometry
#define HT 8             // output rows per block
#define WT 64            // output px per block
#define RI 12            // staged rows (HT + 4)
#define WI 68            // staged cols (WT + 4)
#define NSITE     (2 * RI * WI)   // 1632 16B sites
#define NLD       26              // ceil(1632/64) gload_lds16 per block
#define NSITE_PAD (NLD * 64)      // 1664 sites = 26624 B LDS

typedef __attribute__((ext_vector_type(8))) short bf16x8;
typedef __attribute__((ext_vector_type(4))) float f32x4;
typedef __attribute__((ext_vector_type(4))) int   i32x4;

union I4S8 { i32x4 i; bf16x8 s; };

__device__ __forceinline__ unsigned cvt_pk_bf16(float lo, float hi) {
    unsigned r;
    asm("v_cvt_pk_bf16_f32 %0, %1, %2" : "=v"(r) : "v"(lo), "v"(hi));
    return r;
}

// ---------------- pass 1: NCHW fp32 -> padded NHWC bf16 ---------------------
__global__ __launch_bounds__(256)
void repack_pad_nhwc(const float* __restrict__ x,
                     unsigned short* __restrict__ ws)
{
    const int n   = blockIdx.y;
    const int b   = blockIdx.x;          // 0..255 interior (2 rows each), 256 = borders
    const int tid = threadIdx.x;
    unsigned short* __restrict__ wn = ws + (size_t)n * ((size_t)PROWS * PCOLS * CH);

    if (b < 256) {
        const int r   = 2 * b + (tid >> 7);   // input row 0..511
        const int t   = tid & 127;            // col-quad id 0..127
        const int wq  = t * 4;                // input cols wq..wq+3 (aligned)
        const float* __restrict__ xp = x + (size_t)n * CHIMG + (size_t)r * WW + wq;
        f32x4 v[16];
#pragma unroll
        for (int c = 0; c < 16; ++c)
            v[c] = *(const f32x4*)(xp + (size_t)c * IMG);   // 16 independent dwordx4

        // write cols cp = wq+2 .. wq+5, row rp = r+2 ; 8 aligned 16B stores
        i32x4* __restrict__ dst =
            (i32x4*)wn + ((size_t)(r + 2) * PCOLS + (wq + 2)) * 2;
#pragma unroll
        for (int q = 0; q < 4; ++q) {
            i32x4 lo, hi;
            lo.x = (int)cvt_pk_bf16(v[0][q],  v[1][q]);
            lo.y = (int)cvt_pk_bf16(v[2][q],  v[3][q]);
            lo.z = (int)cvt_pk_bf16(v[4][q],  v[5][q]);
            lo.w = (int)cvt_pk_bf16(v[6][q],  v[7][q]);
            hi.x = (int)cvt_pk_bf16(v[8][q],  v[9][q]);
            hi.y = (int)cvt_pk_bf16(v[10][q], v[11][q]);
            hi.z = (int)cvt_pk_bf16(v[12][q], v[13][q]);
            hi.w = (int)cvt_pk_bf16(v[14][q], v[15][q]);
            dst[2 * q]     = lo;   // ch 0..7
            dst[2 * q + 1] = hi;   // ch 8..15
        }
    } else {
        // zero borders (written every call; ws is not preserved across replays)
        const i32x4 z = (i32x4){0, 0, 0, 0};
        i32x4* __restrict__ w4 = (i32x4*)wn;
        // rows {0,1,514,515,516} x all 520 cols x 2 halves
        for (int zi = tid; zi < 5 * PCOLS * 2; zi += 256) {
            const int rr  = zi / (PCOLS * 2);
            const int rem = zi - rr * (PCOLS * 2);
            const int rp  = rr < 2 ? rr : 512 + rr;     // 0,1,514,515,516
            w4[(size_t)rp * (PCOLS * 2) + rem] = z;
        }
        // rows 2..513 x cols {0,1,514..519} x 2 halves
        for (int zi = tid; zi < 512 * 8 * 2; zi += 256) {
            const int r2   = zi >> 4;
            const int rem  = zi & 15;
            const int csel = rem >> 1;
            const int cp   = csel < 2 ? csel : 512 + csel;   // 0,1,514..519
            w4[((size_t)(2 + r2) * PCOLS + cp) * 2 + (rem & 1)] = z;
        }
    }
}

// ---------------- pass 2: gload_lds16-staged LDS MFMA conv ------------------
// NOTE (R2): never cap VGPRs via __launch_bounds__ min-waves — acc spills.
__global__ __launch_bounds__(256)
void conv_lds_mfma(const unsigned short* __restrict__ ws,
                   const float* __restrict__ fw,
                   float* __restrict__ out)
{
    __shared__ i32x4 xl[NSITE_PAD];   // 26624 B -> 6 blocks/CU

    const int tid  = threadIdx.x;
    const int wv   = tid >> 6;
    const int lane = tid & 63;

    // Bijective XCD swizzle: 8192 = 8 XCDs x 1024 contiguous (2 images each).
    const int bid = blockIdx.x;
    const int swz = ((bid & 7) << 10) | (bid >> 3);
    const int n  = swz >> 9;          // 0..15
    const int ht = (swz >> 3) & 63;   // 0..63
    const int wt = swz & 7;           // 0..7
    const int h0 = ht * HT;
    const int w0 = wt * WT;

    const i32x4* __restrict__ wsn =
        (const i32x4*)ws + (size_t)n * ((size_t)PROWS * PCOLS * 2);

    // ---- staging: 26 global_load_lds dwordx4, LDS dest linear --------------
    // site s = ihl*816 + ri*68 + ci  <->  global site ((h0+ri)*520+(w0+ci))*2+ihl
#pragma unroll
    for (int uu = 0; uu < 7; ++uu) {
        const int u = uu * 4 + wv;               // wave-uniform instr id
        if (u < NLD) {
            int s = u * 64 + lane;
            s = s > NSITE - 1 ? NSITE - 1 : s;   // pad lanes: duplicate load
            const int ihl = s / (RI * WI);
            const int rem = s - ihl * (RI * WI);
            const int ri  = rem / WI;
            const int ci  = rem - ri * WI;
            const i32x4* src =
                wsn + (((size_t)(h0 + ri) * PCOLS + (w0 + ci)) * 2 + ihl);
            __builtin_amdgcn_global_load_lds(
                (const __attribute__((address_space(1))) void*)src,
                (__attribute__((address_space(3))) void*)(xl + u * 64), 16, 0, 0);
        }
    }

    // ---- W fragments (B operand) — verified R5-R9. tap==5 -> zero ----------
    const int px  = lane & 15;
    const int ihl = (lane >> 4) & 1;
    const int tb  = lane >> 5;

    bf16x8 wfrag[3];
#pragma unroll
    for (int s = 0; s < 3; ++s) {
        const int tap = 2 * s + tb;
        I4S8 a;
        a.i = (i32x4){0, 0, 0, 0};
        if (tap < KK) {
            const float* __restrict__ wp = fw + ((size_t)px * CH + ihl * 8) * KK + tap;
            a.i.x = (int)cvt_pk_bf16(wp[0 * KK], wp[1 * KK]);
            a.i.y = (int)cvt_pk_bf16(wp[2 * KK], wp[3 * KK]);
            a.i.z = (int)cvt_pk_bf16(wp[4 * KK], wp[5 * KK]);
            a.i.w = (int)cvt_pk_bf16(wp[6 * KK], wp[7 * KK]);
        }
        wfrag[s] = a.s;
    }

    __syncthreads();   // drains gload_lds (vmcnt) + fw loads

    // ---- hot loop: per wave 2 h-rows x 4 w-tiles, 3 ds_read + 3 MFMA each --
    float* __restrict__ outn = out + (size_t)n * CHIMG;
    const int o  = lane & 15;
    const int pq = (lane >> 4) << 2;
    const int ib = ihl * (RI * WI);

#pragma unroll
    for (int rr = 0; rr < 2; ++rr) {
        const int rloc = wv * 2 + rr;
        const int h    = h0 + rloc;
#pragma unroll
        for (int g = 0; g < 4; ++g) {
            f32x4 acc = (f32x4){0.f, 0.f, 0.f, 0.f};
#pragma unroll
            for (int s = 0; s < 3; ++s) {
                const int tap = 2 * s + tb;
                int ri = rloc + tap;
                ri = ri > RI - 1 ? RI - 1 : ri;           // tap-5 pad lanes only
                int ci = g * 16 + px + tap;
                ci = ci > WI - 1 ? WI - 1 : ci;           // tap-5 pad lanes only
                I4S8 b;
                b.i = xl[ib + ri * WI + ci];              // ds_read_b128, <=2-way
                acc = __builtin_amdgcn_mfma_f32_16x16x32_bf16(
                    b.s, wfrag[s], acc, 0, 0, 0);
            }
            *(f32x4*)(outn + (size_t)o * IMG + (size_t)h * WW +
                      (w0 + g * 16 + pq)) = acc;
        }
    }
}

// ---------------- fallback (R5 kernel, proven 157 us) -----------------------
#define F_RI 20
#define F_WI 68

__global__ __launch_bounds__(256)
void fallback_r5(const float* __restrict__ x,
                 const float* __restrict__ fw,
                 float* __restrict__ out)
{
    __shared__ i32x4 xl[40 * F_WI];

    const int tid = threadIdx.x;
    const int bid = blockIdx.x;
    const int swz = ((bid & 7) << 9) | (bid >> 3);
    const int n  = swz >> 8;
    const int ht = (swz >> 3) & 31;
    const int wt = swz & 7;
    const int h0 = ht * 16;
    const int w0 = wt * 64;

    const int wv   = tid >> 6;
    const int lane = tid & 63;

    const float* __restrict__ xn = x + (size_t)n * CHIMG;

#pragma unroll
    for (int u = 0; u < 10; ++u) {
        const int unit = u * 4 + wv;
        const int ri = unit >> 1;
        const int ih = unit & 1;
        const int r  = h0 - 2 + ri;
        const int w  = w0 - 2 + lane;
        const bool ok = ((unsigned)r < (unsigned)HH) & ((unsigned)w < (unsigned)WW);
        const int rc = r < 0 ? 0 : (r > HH - 1 ? HH - 1 : r);
        const int wc = w < 0 ? 0 : (w > WW - 1 ? WW - 1 : w);
        const float* __restrict__ p8 = xn + (size_t)(ih * 8) * IMG + (size_t)rc * WW + wc;
        float v0 = p8[0 * (size_t)IMG], v1 = p8[1 * (size_t)IMG];
        float v2 = p8[2 * (size_t)IMG], v3 = p8[3 * (size_t)IMG];
        float v4 = p8[4 * (size_t)IMG], v5 = p8[5 * (size_t)IMG];
        float v6 = p8[6 * (size_t)IMG], v7 = p8[7 * (size_t)IMG];
        if (!ok) { v0=v1=v2=v3=v4=v5=v6=v7 = 0.f; }
        i32x4 pk;
        pk.x = (int)cvt_pk_bf16(v0, v1);
        pk.y = (int)cvt_pk_bf16(v2, v3);
        pk.z = (int)cvt_pk_bf16(v4, v5);
        pk.w = (int)cvt_pk_bf16(v6, v7);
        xl[unit * F_WI + lane] = pk;
    }
    if (tid < 160) {
        const int ri  = tid >> 3;
        const int rem = tid & 7;
        const int wi  = 64 + (rem & 3);
        const int ih  = rem >> 2;
        const int r   = h0 - 2 + ri;
        const int w   = w0 - 2 + wi;
        const bool ok = ((unsigned)r < (unsigned)HH) & ((unsigned)w < (unsigned)WW);
        const int rc = r < 0 ? 0 : (r > HH - 1 ? HH - 1 : r);
        const int wc = w < 0 ? 0 : (w > WW - 1 ? WW - 1 : w);
        const float* __restrict__ p8 = xn + (size_t)(ih * 8) * IMG + (size_t)rc * WW + wc;
        float v0 = p8[0 * (size_t)IMG], v1 = p8[1 * (size_t)IMG];
        float v2 = p8[2 * (size_t)IMG], v3 = p8[3 * (size_t)IMG];
        float v4 = p8[4 * (size_t)IMG], v5 = p8[5 * (size_t)IMG];
        float v6 = p8[6 * (size_t)IMG], v7 = p8[7 * (size_t)IMG];
        if (!ok) { v0=v1=v2=v3=v4=v5=v6=v7 = 0.f; }
        i32x4 pk;
        pk.x = (int)cvt_pk_bf16(v0, v1);
        pk.y = (int)cvt_pk_bf16(v2, v3);
        pk.z = (int)cvt_pk_bf16(v4, v5);
        pk.w = (int)cvt_pk_bf16(v6, v7);
        xl[(ri * 2 + ih) * F_WI + wi] = pk;
    }

    const int px  = lane & 15;
    const int ihl = (lane >> 4) & 1;
    const int tb  = lane >> 5;

    bf16x8 afrag[3];
#pragma unroll
    for (int s = 0; s < 3; ++s) {
        const int tap = 2 * s + tb;
        I4S8 a;
        a.i = (i32x4){0, 0, 0, 0};
        if (tap < KK) {
            const float* __restrict__ wp = fw + ((size_t)px * CH + ihl * 8) * KK + tap;
            a.i.x = (int)cvt_pk_bf16(wp[0 * KK], wp[1 * KK]);
            a.i.y = (int)cvt_pk_bf16(wp[2 * KK], wp[3 * KK]);
            a.i.z = (int)cvt_pk_bf16(wp[4 * KK], wp[5 * KK]);
            a.i.w = (int)cvt_pk_bf16(wp[6 * KK], wp[7 * KK]);
        }
        afrag[s] = a.s;
    }

    __syncthreads();

    f32x4 acc[4][4];
#pragma unroll
    for (int yy = 0; yy < 4; ++yy)
#pragma unroll
        for (int g = 0; g < 4; ++g) acc[yy][g] = (f32x4){0.f, 0.f, 0.f, 0.f};

    const int ybase = wv * 4;
#pragma unroll
    for (int yy = 0; yy < 4; ++yy) {
#pragma unroll
        for (int s = 0; s < 3; ++s) {
            const int tap = 2 * s + tb;
            int ri = ybase + yy + tap;
            ri = ri > F_RI - 1 ? F_RI - 1 : ri;
            const int c = ri * 2 + ihl;
#pragma unroll
            for (int g = 0; g < 4; ++g) {
                int wi = g * 16 + px + tap;
                wi = wi > F_WI - 1 ? F_WI - 1 : wi;
                I4S8 b;
                b.i = xl[c * F_WI + wi];
                acc[yy][g] = __builtin_amdgcn_mfma_f32_16x16x32_bf16(
                    b.s, afrag[s], acc[yy][g], 0, 0, 0);
            }
        }
    }

    float* __restrict__ on = out + (size_t)n * CHIMG;
    const int o  = lane & 15;
    const int pq = (lane >> 4) << 2;
#pragma unroll
    for (int yy = 0; yy < 4; ++yy) {
        const int h = h0 + ybase + yy;
#pragma unroll
        for (int g = 0; g < 4; ++g) {
            float* __restrict__ dst =
                on + (size_t)o * IMG + (size_t)h * WW + (w0 + g * 16 + pq);
            *(f32x4*)dst = acc[yy][g];
        }
    }
}

extern "C" void kernel_launch(void* const* d_in, const int* in_sizes, int n_in,
                              void* d_out, int out_size, void* d_ws, size_t ws_size,
                              hipStream_t stream)
{
    const float* x  = (const float*)d_in[0];
    const float* fw = (const float*)d_in[1];
    float* out      = (float*)d_out;

    if (ws_size >= NEED_WS) {
        unsigned short* ws = (unsigned short*)d_ws;
        repack_pad_nhwc<<<dim3(257, 16), dim3(256), 0, stream>>>(x, ws);
        conv_lds_mfma<<<dim3(8192), dim3(256), 0, stream>>>(ws, fw, out);
    } else {
        fallback_r5<<<dim3(4096), dim3(256), 0, stream>>>(x, fw, out);
    }
}